// Round 2
// baseline (255.562 us; speedup 1.0000x reference)
//
#include <hip/hip_runtime.h>

namespace {

constexpr int B = 16, C = 3, H = 512, W = 1024;
constexpr int HW = H * W;                 // 2^19
constexpr int NPIX = B * HW;              // 8388608
constexpr int BLOCK = 256;
constexpr int PX = 4;                     // pixels per thread (block = one row)
constexpr int GRID = NPIX / (BLOCK * PX); // 8192

__global__ __launch_bounds__(BLOCK) void flow_loss_partial(
    const float* __restrict__ flow,   // (B,H,W,2)
    const float* __restrict__ im1,    // (B,C,H,W)
    const float* __restrict__ im2,    // (B,C,H,W)
    float* __restrict__ partials)     // [GRID]
{
    const int t  = blockIdx.x * BLOCK + threadIdx.x;
    const int p0 = t * PX;                // first pixel of this thread
    const int b    = p0 >> 19;            // / HW
    const int rem0 = p0 & (HW - 1);
    const int y    = rem0 >> 10;          // / W   (same row for all PX pixels)
    const int x0b  = rem0 & (W - 1);

    // ---- flow: 2x float4 = 4 pixels of (fx,fy) ----
    const float4 fA = *reinterpret_cast<const float4*>(flow + 2 * p0);
    const float4 fB = *reinterpret_cast<const float4*>(flow + 2 * p0 + 4);
    const float fx[PX] = { fA.x, fA.z, fB.x, fB.z };
    const float fy[PX] = { fA.y, fA.w, fB.y, fB.w };

    const float base_y = (float)y / (float)H * 2.0f - 1.0f;
    const float gy_c   = fy[0] / (float)H + base_y;           // per-px below

    int   off[PX][4];
    float wgt[PX][4];

#pragma unroll
    for (int p = 0; p < PX; ++p) {
        const int x = x0b + p;
        // replicate reference arithmetic sequence (f32)
        const float base_x = (float)x / (float)W * 2.0f - 1.0f;
        const float gx = fx[p] / (float)W + base_x;
        const float gy = fy[p] / (float)H + base_y;
        const float ix = ((gx + 1.0f) * (float)W - 1.0f) * 0.5f;
        const float iy = ((gy + 1.0f) * (float)H - 1.0f) * 0.5f;

        const float x0f = floorf(ix);
        const float y0f = floorf(iy);
        const float wx1 = ix - x0f, wx0 = 1.0f - wx1;
        const float wy1 = iy - y0f, wy0 = 1.0f - wy1;

        const int xi0 = (int)x0f, yi0 = (int)y0f;
        const int xi1 = xi0 + 1,  yi1 = yi0 + 1;

        const bool vx0 = (xi0 >= 0) & (xi0 < W);
        const bool vx1 = (xi1 >= 0) & (xi1 < W);
        const bool vy0 = (yi0 >= 0) & (yi0 < H);
        const bool vy1 = (yi1 >= 0) & (yi1 < H);

        wgt[p][0] = wx0 * wy0 * (float)(vx0 & vy0);
        wgt[p][1] = wx1 * wy0 * (float)(vx1 & vy0);
        wgt[p][2] = wx0 * wy1 * (float)(vx0 & vy1);
        wgt[p][3] = wx1 * wy1 * (float)(vx1 & vy1);

        const int x0c = min(max(xi0, 0), W - 1);
        const int x1c = min(max(xi1, 0), W - 1);
        const int y0c = min(max(yi0, 0), H - 1);
        const int y1c = min(max(yi1, 0), H - 1);

        off[p][0] = y0c * W + x0c;
        off[p][1] = y0c * W + x1c;
        off[p][2] = y1c * W + x0c;
        off[p][3] = y1c * W + x1c;
    }
    (void)gy_c;

    const float* p1 = im1 + b * C * HW;
    const float* p2 = im2 + b * C * HW;

    float acc = 0.0f;

#pragma unroll
    for (int c = 0; c < C; ++c) {
        const float* __restrict__ pl = p1 + c * HW;

        // issue all 16 gathers + the coalesced im2 float4 for this channel
        float g[PX][4];
#pragma unroll
        for (int p = 0; p < PX; ++p) {
#pragma unroll
            for (int k = 0; k < 4; ++k) g[p][k] = pl[off[p][k]];
        }
        const float4 v2 = *reinterpret_cast<const float4*>(p2 + c * HW + rem0);
        const float v2a[PX] = { v2.x, v2.y, v2.z, v2.w };

#pragma unroll
        for (int p = 0; p < PX; ++p) {
            const float warp = wgt[p][0] * g[p][0] + wgt[p][1] * g[p][1]
                             + wgt[p][2] * g[p][2] + wgt[p][3] * g[p][3];
            acc += fabsf(v2a[p] - warp);
        }
    }

    // wave64 reduce
#pragma unroll
    for (int o = 32; o > 0; o >>= 1)
        acc += __shfl_down(acc, o, 64);

    __shared__ float lds[BLOCK / 64];
    const int lane = threadIdx.x & 63;
    const int wid  = threadIdx.x >> 6;
    if (lane == 0) lds[wid] = acc;
    __syncthreads();
    if (threadIdx.x == 0) {
        float s = 0.0f;
#pragma unroll
        for (int wv = 0; wv < BLOCK / 64; ++wv) s += lds[wv];
        partials[blockIdx.x] = s;
    }
}

__global__ __launch_bounds__(BLOCK) void flow_loss_reduce(
    const float* __restrict__ partials, float* __restrict__ out)
{
    __shared__ double lds[BLOCK];
    double s = 0.0;
    for (int i = threadIdx.x; i < GRID; i += BLOCK) s += (double)partials[i];
    lds[threadIdx.x] = s;
    __syncthreads();
    for (int o = BLOCK / 2; o > 0; o >>= 1) {
        if (threadIdx.x < o) lds[threadIdx.x] += lds[threadIdx.x + o];
        __syncthreads();
    }
    if (threadIdx.x == 0) out[0] = (float)(lds[0] / (double)(W * H));
}

} // namespace

extern "C" void kernel_launch(void* const* d_in, const int* in_sizes, int n_in,
                              void* d_out, int out_size, void* d_ws, size_t ws_size,
                              hipStream_t stream) {
    const float* flow = (const float*)d_in[0];
    const float* im1  = (const float*)d_in[1];
    const float* im2  = (const float*)d_in[2];
    float* out = (float*)d_out;
    float* partials = (float*)d_ws;

    flow_loss_partial<<<GRID, BLOCK, 0, stream>>>(flow, im1, im2, partials);
    flow_loss_reduce<<<1, BLOCK, 0, stream>>>(partials, out);
}

// Round 3
// 182.189 us; speedup vs baseline: 1.4027x; 1.4027x over previous
//
#include <hip/hip_runtime.h>

namespace {

constexpr int B = 16, C = 3, H = 512, W = 1024;
constexpr int HW = H * W;                 // 2^19
constexpr int NPIX = B * HW;              // 8388608
constexpr int BLOCK = 256;
constexpr int GRID = 2048;
constexpr int NPAIR = NPIX / 2;           // 2 pixels per thread-iteration
constexpr int STRIDE = GRID * BLOCK;      // pair-index stride

__global__ __launch_bounds__(BLOCK, 4) void flow_loss_partial(
    const float* __restrict__ flow,   // (B,H,W,2)
    const float* __restrict__ im1,    // (B,C,H,W)
    const float* __restrict__ im2,    // (B,C,H,W)
    float* __restrict__ partials)     // [GRID]
{
    float acc = 0.0f;

    for (int t = blockIdx.x * BLOCK + threadIdx.x; t < NPAIR; t += STRIDE) {
        const int p0  = t << 1;               // first pixel (even x)
        const int b   = p0 >> 19;             // / HW
        const int rem = p0 & (HW - 1);
        const int y   = rem >> 10;            // / W
        const int x0b = rem & (W - 1);

        const float4 f = *reinterpret_cast<const float4*>(flow + 2 * p0);
        // pixel 0: (f.x, f.y)   pixel 1: (f.z, f.w)

        const float base_y = (float)y / (float)H * 2.0f - 1.0f;
        const float iyc = ((base_y + 1.0f) * (float)H - 1.0f) * 0.5f; // = y - 0.5 exactly? no: keep per-pixel form

        // ---------- pixel 0 ----------
        const float base_x0 = (float)x0b / (float)W * 2.0f - 1.0f;
        const float gx0 = f.x / (float)W + base_x0;
        const float gy0 = f.y / (float)H + base_y;
        const float ix_0 = ((gx0 + 1.0f) * (float)W - 1.0f) * 0.5f;
        const float iy_0 = ((gy0 + 1.0f) * (float)H - 1.0f) * 0.5f;
        const float x0f_0 = floorf(ix_0), y0f_0 = floorf(iy_0);
        const float wx1_0 = ix_0 - x0f_0, wx0_0 = 1.0f - wx1_0;
        const float wy1_0 = iy_0 - y0f_0, wy0_0 = 1.0f - wy1_0;
        const int xi0_0 = (int)x0f_0, yi0_0 = (int)y0f_0;
        const int xi1_0 = xi0_0 + 1,  yi1_0 = yi0_0 + 1;
        const bool vx0_0 = (xi0_0 >= 0) & (xi0_0 < W);
        const bool vx1_0 = (xi1_0 >= 0) & (xi1_0 < W);
        const bool vy0_0 = (yi0_0 >= 0) & (yi0_0 < H);
        const bool vy1_0 = (yi1_0 >= 0) & (yi1_0 < H);
        const float w00_0 = wx0_0 * wy0_0 * (float)(vx0_0 & vy0_0);
        const float w01_0 = wx1_0 * wy0_0 * (float)(vx1_0 & vy0_0);
        const float w10_0 = wx0_0 * wy1_0 * (float)(vx0_0 & vy1_0);
        const float w11_0 = wx1_0 * wy1_0 * (float)(vx1_0 & vy1_0);
        const int x0c_0 = min(max(xi0_0, 0), W - 1);
        const int x1c_0 = min(max(xi1_0, 0), W - 1);
        const int y0c_0 = min(max(yi0_0, 0), H - 1);
        const int y1c_0 = min(max(yi1_0, 0), H - 1);
        const int o00_0 = y0c_0 * W + x0c_0;
        const int o01_0 = y0c_0 * W + x1c_0;
        const int o10_0 = y1c_0 * W + x0c_0;
        const int o11_0 = y1c_0 * W + x1c_0;

        // ---------- pixel 1 ----------
        const float base_x1 = (float)(x0b + 1) / (float)W * 2.0f - 1.0f;
        const float gx1 = f.z / (float)W + base_x1;
        const float gy1 = f.w / (float)H + base_y;
        const float ix_1 = ((gx1 + 1.0f) * (float)W - 1.0f) * 0.5f;
        const float iy_1 = ((gy1 + 1.0f) * (float)H - 1.0f) * 0.5f;
        const float x0f_1 = floorf(ix_1), y0f_1 = floorf(iy_1);
        const float wx1_1 = ix_1 - x0f_1, wx0_1 = 1.0f - wx1_1;
        const float wy1_1 = iy_1 - y0f_1, wy0_1 = 1.0f - wy1_1;
        const int xi0_1 = (int)x0f_1, yi0_1 = (int)y0f_1;
        const int xi1_1 = xi0_1 + 1,  yi1_1 = yi0_1 + 1;
        const bool vx0_1 = (xi0_1 >= 0) & (xi0_1 < W);
        const bool vx1_1 = (xi1_1 >= 0) & (xi1_1 < W);
        const bool vy0_1 = (yi0_1 >= 0) & (yi0_1 < H);
        const bool vy1_1 = (yi1_1 >= 0) & (yi1_1 < H);
        const float w00_1 = wx0_1 * wy0_1 * (float)(vx0_1 & vy0_1);
        const float w01_1 = wx1_1 * wy0_1 * (float)(vx1_1 & vy0_1);
        const float w10_1 = wx0_1 * wy1_1 * (float)(vx0_1 & vy1_1);
        const float w11_1 = wx1_1 * wy1_1 * (float)(vx1_1 & vy1_1);
        const int x0c_1 = min(max(xi0_1, 0), W - 1);
        const int x1c_1 = min(max(xi1_1, 0), W - 1);
        const int y0c_1 = min(max(yi0_1, 0), H - 1);
        const int y1c_1 = min(max(yi1_1, 0), H - 1);
        const int o00_1 = y0c_1 * W + x0c_1;
        const int o01_1 = y0c_1 * W + x1c_1;
        const int o10_1 = y1c_1 * W + x0c_1;
        const int o11_1 = y1c_1 * W + x1c_1;

        const float* __restrict__ p1 = im1 + b * C * HW;
        const float* __restrict__ p2 = im2 + b * C * HW + rem;

        // ---- batch ALL loads (24 gathers + 3 coalesced float2) ----
        const float* __restrict__ pl0 = p1;
        const float* __restrict__ pl1 = p1 + HW;
        const float* __restrict__ pl2 = p1 + 2 * HW;

        const float g00a = pl0[o00_0], g01a = pl0[o01_0], g10a = pl0[o10_0], g11a = pl0[o11_0];
        const float g00b = pl0[o00_1], g01b = pl0[o01_1], g10b = pl0[o10_1], g11b = pl0[o11_1];
        const float h00a = pl1[o00_0], h01a = pl1[o01_0], h10a = pl1[o10_0], h11a = pl1[o11_0];
        const float h00b = pl1[o00_1], h01b = pl1[o01_1], h10b = pl1[o10_1], h11b = pl1[o11_1];
        const float k00a = pl2[o00_0], k01a = pl2[o01_0], k10a = pl2[o10_0], k11a = pl2[o11_0];
        const float k00b = pl2[o00_1], k01b = pl2[o01_1], k10b = pl2[o10_1], k11b = pl2[o11_1];

        const float2 v2_0 = *reinterpret_cast<const float2*>(p2);
        const float2 v2_1 = *reinterpret_cast<const float2*>(p2 + HW);
        const float2 v2_2 = *reinterpret_cast<const float2*>(p2 + 2 * HW);

        // ---- compute ----
        const float wa0 = ((w00_0 * g00a + w01_0 * g01a) + w10_0 * g10a) + w11_0 * g11a;
        const float wa1 = ((w00_1 * g00b + w01_1 * g01b) + w10_1 * g10b) + w11_1 * g11b;
        const float wb0 = ((w00_0 * h00a + w01_0 * h01a) + w10_0 * h10a) + w11_0 * h11a;
        const float wb1 = ((w00_1 * h00b + w01_1 * h01b) + w10_1 * h10b) + w11_1 * h11b;
        const float wc0 = ((w00_0 * k00a + w01_0 * k01a) + w10_0 * k10a) + w11_0 * k11a;
        const float wc1 = ((w00_1 * k00b + w01_1 * k01b) + w10_1 * k10b) + w11_1 * k11b;

        acc += fabsf(v2_0.x - wa0) + fabsf(v2_0.y - wa1)
             + fabsf(v2_1.x - wb0) + fabsf(v2_1.y - wb1)
             + fabsf(v2_2.x - wc0) + fabsf(v2_2.y - wc1);
    }

    // wave64 reduce
#pragma unroll
    for (int o = 32; o > 0; o >>= 1)
        acc += __shfl_down(acc, o, 64);

    __shared__ float lds[BLOCK / 64];
    const int lane = threadIdx.x & 63;
    const int wid  = threadIdx.x >> 6;
    if (lane == 0) lds[wid] = acc;
    __syncthreads();
    if (threadIdx.x == 0) {
        float s = 0.0f;
#pragma unroll
        for (int wv = 0; wv < BLOCK / 64; ++wv) s += lds[wv];
        partials[blockIdx.x] = s;
    }
}

__global__ __launch_bounds__(BLOCK) void flow_loss_reduce(
    const float* __restrict__ partials, float* __restrict__ out)
{
    __shared__ double lds[BLOCK];
    double s = 0.0;
    for (int i = threadIdx.x; i < GRID; i += BLOCK) s += (double)partials[i];
    lds[threadIdx.x] = s;
    __syncthreads();
    for (int o = BLOCK / 2; o > 0; o >>= 1) {
        if (threadIdx.x < o) lds[threadIdx.x] += lds[threadIdx.x + o];
        __syncthreads();
    }
    if (threadIdx.x == 0) out[0] = (float)(lds[0] / (double)(W * H));
}

} // namespace

extern "C" void kernel_launch(void* const* d_in, const int* in_sizes, int n_in,
                              void* d_out, int out_size, void* d_ws, size_t ws_size,
                              hipStream_t stream) {
    const float* flow = (const float*)d_in[0];
    const float* im1  = (const float*)d_in[1];
    const float* im2  = (const float*)d_in[2];
    float* out = (float*)d_out;
    float* partials = (float*)d_ws;

    flow_loss_partial<<<GRID, BLOCK, 0, stream>>>(flow, im1, im2, partials);
    flow_loss_reduce<<<1, BLOCK, 0, stream>>>(partials, out);
}

// Round 4
// 122.881 us; speedup vs baseline: 2.0798x; 1.4826x over previous
//
#include <hip/hip_runtime.h>

namespace {

constexpr int B = 16, C = 3, H = 512, W = 1024;
constexpr int HW = H * W;                 // 2^19
constexpr int NPIX = B * HW;              // 8388608
constexpr int BLOCK = 256;
constexpr int GRID = 2048;                // 256 CU x 8 blocks, grid-stride

// 4B-aligned float2 load (x0/x1 corners are adjacent floats at arbitrary
// dword offset). packed+aligned(4) tells LLVM align=4; gfx950 global loads
// support dword-aligned dwordx2.
__device__ __forceinline__ float2 ld2(const float* __restrict__ p) {
    struct __attribute__((packed, aligned(4))) F2 { float a, b; };
    const F2 v = *reinterpret_cast<const F2*>(p);
    return make_float2(v.a, v.b);
}

__global__ __launch_bounds__(BLOCK) void flow_loss_partial(
    const float* __restrict__ flow,   // (B,H,W,2)
    const float* __restrict__ im1,    // (B,C,H,W)
    const float* __restrict__ im2,    // (B,C,H,W)
    float* __restrict__ partials)     // [GRID]
{
    float acc = 0.0f;

    for (int i = blockIdx.x * BLOCK + threadIdx.x; i < NPIX; i += GRID * BLOCK) {
        const int b   = i >> 19;          // / HW
        const int rem = i & (HW - 1);
        const int y   = rem >> 10;        // / W
        const int x   = rem & (W - 1);

        const float2 f = *reinterpret_cast<const float2*>(flow + 2 * i);

        // Replicate reference arithmetic sequence exactly (f32 ops).
        const float base_x = (float)x / (float)W * 2.0f - 1.0f;
        const float base_y = (float)y / (float)H * 2.0f - 1.0f;
        const float gx = f.x / (float)W + base_x;
        const float gy = f.y / (float)H + base_y;
        const float ix = ((gx + 1.0f) * (float)W - 1.0f) * 0.5f;
        const float iy = ((gy + 1.0f) * (float)H - 1.0f) * 0.5f;

        const float x0f = floorf(ix);
        const float y0f = floorf(iy);
        const float wx1 = ix - x0f, wx0 = 1.0f - wx1;
        const float wy1 = iy - y0f, wy0 = 1.0f - wy1;

        const int x0 = (int)x0f, y0 = (int)y0f;
        const int x1 = x0 + 1,   y1 = y0 + 1;

        const bool vx0 = (x0 >= 0) & (x0 < W);
        const bool vx1 = (x1 >= 0) & (x1 < W);
        const bool vy0 = (y0 >= 0) & (y0 < H);
        const bool vy1 = (y1 >= 0) & (y1 < H);

        const float w00 = wx0 * wy0 * (float)(vx0 & vy0);
        const float w01 = wx1 * wy0 * (float)(vx1 & vy0);
        const float w10 = wx0 * wy1 * (float)(vx0 & vy1);
        const float w11 = wx1 * wy1 * (float)(vx1 & vy1);

        // Merged-corner addressing: x1 = x0+1 are adjacent floats.
        // Load float2 at xL = clamp(x0, 0, W-2); select each corner from
        // .x/.y. Wherever the clamp breaks adjacency, that corner's weight
        // is exactly 0 and the loaded value is finite, so the result is
        // bit-identical to the reference.
        const int xL  = min(max(x0, 0), W - 2);
        const int x0c = min(max(x0, 0), W - 1);
        const int x1c = min(max(x1, 0), W - 1);
        const int y0c = min(max(y0, 0), H - 1);
        const int y1c = min(max(y1, 0), H - 1);
        const bool s0 = (x0c != xL);      // corner x0 -> .y half?
        const bool s1 = (x1c != xL);      // corner x1 -> .y half?

        const int oT = y0c * W + xL;      // top row pair
        const int oB = y1c * W + xL;      // bottom row pair

        const float* __restrict__ p1 = im1 + b * C * HW;
        const float* __restrict__ p2 = im2 + b * C * HW + rem;

        // ---- issue all loads: 6 float2 gathers + 3 coalesced im2 + done ----
        const float2 t0 = ld2(p1 + oT);
        const float2 b0 = ld2(p1 + oB);
        const float2 t1 = ld2(p1 + HW + oT);
        const float2 b1 = ld2(p1 + HW + oB);
        const float2 t2 = ld2(p1 + 2 * HW + oT);
        const float2 b2 = ld2(p1 + 2 * HW + oB);
        const float z0 = p2[0];
        const float z1 = p2[HW];
        const float z2 = p2[2 * HW];

        // ---- bilinear + |diff| per channel ----
        {
            const float v00 = s0 ? t0.y : t0.x;
            const float v01 = s1 ? t0.y : t0.x;
            const float v10 = s0 ? b0.y : b0.x;
            const float v11 = s1 ? b0.y : b0.x;
            const float wp = w00 * v00 + w01 * v01 + w10 * v10 + w11 * v11;
            acc += fabsf(z0 - wp);
        }
        {
            const float v00 = s0 ? t1.y : t1.x;
            const float v01 = s1 ? t1.y : t1.x;
            const float v10 = s0 ? b1.y : b1.x;
            const float v11 = s1 ? b1.y : b1.x;
            const float wp = w00 * v00 + w01 * v01 + w10 * v10 + w11 * v11;
            acc += fabsf(z1 - wp);
        }
        {
            const float v00 = s0 ? t2.y : t2.x;
            const float v01 = s1 ? t2.y : t2.x;
            const float v10 = s0 ? b2.y : b2.x;
            const float v11 = s1 ? b2.y : b2.x;
            const float wp = w00 * v00 + w01 * v01 + w10 * v10 + w11 * v11;
            acc += fabsf(z2 - wp);
        }
    }

    // wave64 reduce
#pragma unroll
    for (int o = 32; o > 0; o >>= 1)
        acc += __shfl_down(acc, o, 64);

    __shared__ float lds[BLOCK / 64];
    const int lane = threadIdx.x & 63;
    const int wid  = threadIdx.x >> 6;
    if (lane == 0) lds[wid] = acc;
    __syncthreads();
    if (threadIdx.x == 0) {
        float s = 0.0f;
#pragma unroll
        for (int wv = 0; wv < BLOCK / 64; ++wv) s += lds[wv];
        partials[blockIdx.x] = s;
    }
}

__global__ __launch_bounds__(BLOCK) void flow_loss_reduce(
    const float* __restrict__ partials, float* __restrict__ out)
{
    __shared__ double lds[BLOCK];
    double s = 0.0;
    for (int i = threadIdx.x; i < GRID; i += BLOCK) s += (double)partials[i];
    lds[threadIdx.x] = s;
    __syncthreads();
    for (int o = BLOCK / 2; o > 0; o >>= 1) {
        if (threadIdx.x < o) lds[threadIdx.x] += lds[threadIdx.x + o];
        __syncthreads();
    }
    if (threadIdx.x == 0) out[0] = (float)(lds[0] / (double)(W * H));
}

} // namespace

extern "C" void kernel_launch(void* const* d_in, const int* in_sizes, int n_in,
                              void* d_out, int out_size, void* d_ws, size_t ws_size,
                              hipStream_t stream) {
    const float* flow = (const float*)d_in[0];
    const float* im1  = (const float*)d_in[1];
    const float* im2  = (const float*)d_in[2];
    float* out = (float*)d_out;
    float* partials = (float*)d_ws;

    flow_loss_partial<<<GRID, BLOCK, 0, stream>>>(flow, im1, im2, partials);
    flow_loss_reduce<<<1, BLOCK, 0, stream>>>(partials, out);
}